// Round 1
// 771.647 us; speedup vs baseline: 1.1463x; 1.1463x over previous
//
#include <hip/hip_runtime.h>
#include <math.h>

#define PI_F 3.14159265358979323846f

__device__ inline float2 cmulf(float2 a, float2 b) {
    return make_float2(a.x * b.x - a.y * b.y, a.x * b.y + a.y * b.x);
}

// Complex MAC: a += w * v
__device__ inline void cmac(float2& a, float2 w, float2 v) {
    a.x = fmaf(w.x, v.x, a.x);
    a.x = fmaf(-w.y, v.y, a.x);
    a.y = fmaf(w.x, v.y, a.y);
    a.y = fmaf(w.y, v.x, a.y);
}

// 512-point Stockham radix-2 FFT over NCOLS interleaved transforms.
// Data in a[col*512 + i]; b is ping-pong workspace. 256 threads.
// tbl[k] = exp(-2*pi*i*k/512), k in [0,256). inv: conjugate twiddles (no 1/N).
template <int NCOLS>
__device__ inline float2* fft512(float2* a, float2* b, const float2* tbl, int tid, bool inv) {
    for (int st = 0; st < 9; ++st) {
        int p = tid >> st;
        float2 w = tbl[p << st];
        if (inv) w.y = -w.y;
        int i0 = tid;
        int i1 = tid + 256;
        int o0 = tid + ((tid >> st) << st);
        int o1 = o0 + (1 << st);
#pragma unroll
        for (int k = 0; k < NCOLS; ++k) {
            float2 A = a[k * 512 + i0];
            float2 B = a[k * 512 + i1];
            float2 s = make_float2(A.x + B.x, A.y + B.y);
            float2 d = make_float2(A.x - B.x, A.y - B.y);
            b[k * 512 + o0] = s;
            b[k * 512 + o1] = cmulf(d, w);
        }
        __syncthreads();
        float2* t = a; a = b; b = t;
    }
    return a;
}

__device__ inline void build_tbl(float2* tbl, int tid) {
    float ang = -2.0f * PI_F * (float)tid * (1.0f / 512.0f);
    tbl[tid] = make_float2(cosf(ang), sinf(ang));
}

// K1: real FFT of each row of x.
__global__ __launch_bounds__(256) void k_row_rfft(const float* __restrict__ x,
                                                  float2* __restrict__ G) {
    __shared__ float2 b0[512], b1[512], tbl[256];
    int tid = threadIdx.x;
    int row = blockIdx.x;  // nc*512 + h
    build_tbl(tbl, tid);
    const float* xr = x + (size_t)row * 512;
    b0[tid]       = make_float2(xr[tid], 0.0f);
    b0[tid + 256] = make_float2(xr[tid + 256], 0.0f);
    __syncthreads();
    float2* res = fft512<1>(b0, b1, tbl, tid, false);
    float2* g = G + (size_t)row * 257;
    g[tid] = res[tid];
    if (tid == 0) g[256] = res[256];
}

// K2: FFT along h for 4 adjacent columns v0..v0+3.
__global__ __launch_bounds__(256) void k_col_fft(const float2* __restrict__ G,
                                                 float2* __restrict__ XT) {
    __shared__ float2 b0[2048], b1[2048], tbl[256];
    int tid = threadIdx.x;
    int nc = blockIdx.x / 65;
    int v0 = (blockIdx.x % 65) * 4;
    build_tbl(tbl, tid);
#pragma unroll
    for (int i = 0; i < 8; ++i) {
        int e = tid + 256 * i;
        int k = e & 3, h = e >> 2;
        int v = v0 + k;
        float2 val = make_float2(0.0f, 0.0f);
        if (v < 257) val = G[((size_t)nc * 512 + h) * 257 + v];
        b0[k * 512 + h] = val;
    }
    __syncthreads();
    float2* res = fft512<4>(b0, b1, tbl, tid, false);
#pragma unroll
    for (int k = 0; k < 4; ++k) {
        int v = v0 + k;
        if (v < 257) {
            float2* dst = XT + ((size_t)nc * 257 + v) * 512;
            dst[tid]       = res[k * 512 + tid];
            dst[tid + 256] = res[k * 512 + tid + 256];
        }
    }
}

// K3: complex 3x3 conv, 16->16 channels, zero padding, on the half-spectrum.
// Y[o,u,v] = b[o] + sum_{c,kh,kw} w[c,o,kh,kw] * X[c, u-(kh-1), v-(kw-1)]
// NEW STRUCTURE: o is wave-uniform (wave wv owns o = 4*wv .. 4*wv+3, looped in
// registers); lane = u within a 64-wide u-tile. Weights are wave-uniform ->
// scalar (SGPR) loads, no LDS weight buffer. X tile is a linear [c][dv][66]
// LDS array read with contiguous lane-indexed ds_read_b64 (conflict-free).
// LDS = 24.75 KiB -> 6 blocks/CU (vs 2 before).
__global__ __launch_bounds__(256, 6) void k_conv(const float2* __restrict__ XT,
                                                 float2* __restrict__ YT,
                                                 const float* __restrict__ wr,
                                                 const float* __restrict__ wi,
                                                 const float* __restrict__ br,
                                                 const float* __restrict__ bi) {
    __shared__ float2 Xs[16 * 3 * 66];  // [c][dv][uu], linear, no padding
    int tid = threadIdx.x;
    int bid = blockIdx.x;
    int ut = bid & 7;
    int rest = bid >> 3;
    int v = rest % 257;
    int n = rest / 257;
    int u0 = ut * 64;

    // Stage X tile with halo (66 uu per (c,dv) row), zero-padded, linear index.
    for (int l = tid; l < 3168; l += 256) {
        int c = l / 198;
        int rem = l - c * 198;
        int dv = rem / 66;
        int uu = rem - dv * 66;
        int vg = v - 1 + dv;
        int ug = u0 - 1 + uu;
        float2 val = make_float2(0.0f, 0.0f);
        if (vg >= 0 && vg < 257 && ug >= 0 && ug < 512)
            val = XT[(((size_t)n * 16 + c) * 257 + vg) * 512 + ug];
        Xs[l] = val;
    }
    __syncthreads();

    int lane = tid & 63;
    int wv = __builtin_amdgcn_readfirstlane(tid >> 6);  // wave id, uniform
    int o0 = wv * 4;

    float2 acc[4];
#pragma unroll
    for (int oo = 0; oo < 4; ++oo)
        acc[oo] = make_float2(br[o0 + oo], bi[o0 + oo]);  // uniform -> s_load

    for (int c = 0; c < 16; ++c) {
        // Load the 3x3 X window for this lane's u: xv[dv][j] = X[vg=v-1+dv, u+(j-1)]
        float2 xv[3][3];
#pragma unroll
        for (int dv = 0; dv < 3; ++dv) {
            const float2* row = &Xs[(c * 3 + dv) * 66];
            xv[dv][0] = row[lane];       // pairs with kh=2
            xv[dv][1] = row[lane + 1];   // pairs with kh=1
            xv[dv][2] = row[lane + 2];   // pairs with kh=0
        }
#pragma unroll
        for (int oo = 0; oo < 4; ++oo) {
            // weights for (c, o0+oo): 9 contiguous floats each -> scalar loads
            const float* wrp = wr + ((size_t)(c * 16 + o0 + oo)) * 9;
            const float* wip = wi + ((size_t)(c * 16 + o0 + oo)) * 9;
            float wre[9], wim[9];
#pragma unroll
            for (int t = 0; t < 9; ++t) { wre[t] = wrp[t]; wim[t] = wip[t]; }
#pragma unroll
            for (int dv = 0; dv < 3; ++dv) {
                int kw = 2 - dv;  // dv row corresponds to kw = 2-dv
#pragma unroll
                for (int kh = 0; kh < 3; ++kh) {
                    int t = kh * 3 + kw;
                    float2 w = make_float2(wre[t], wim[t]);
                    cmac(acc[oo], w, xv[dv][2 - kh]);
                }
            }
        }
    }

    // Each lane writes 4 output channels at its u; lane-consecutive -> coalesced.
#pragma unroll
    for (int oo = 0; oo < 4; ++oo) {
        YT[(((size_t)n * 16 + o0 + oo) * 257 + v) * 512 + u0 + lane] = acc[oo];
    }
}

// K4: inverse FFT along u (scale 1/512) for 4 columns.
__global__ __launch_bounds__(256) void k_col_ifft(const float2* __restrict__ YT,
                                                  float2* __restrict__ ZT) {
    __shared__ float2 b0[2048], b1[2048], tbl[256];
    int tid = threadIdx.x;
    int no = blockIdx.x / 65;
    int v0 = (blockIdx.x % 65) * 4;
    build_tbl(tbl, tid);
#pragma unroll
    for (int k = 0; k < 4; ++k) {
        int v = v0 + k;
        const float2* src = YT + ((size_t)no * 257 + (v < 257 ? v : 256)) * 512;
        b0[k * 512 + tid]       = src[tid];
        b0[k * 512 + tid + 256] = src[tid + 256];
    }
    __syncthreads();
    float2* res = fft512<4>(b0, b1, tbl, tid, true);
    const float sc = 1.0f / 512.0f;
#pragma unroll
    for (int k = 0; k < 4; ++k) {
        int v = v0 + k;
        if (v < 257) {
            float2* dst = ZT + ((size_t)no * 257 + v) * 512;
            float2 r0 = res[k * 512 + tid];
            float2 r1 = res[k * 512 + tid + 256];
            dst[tid]       = make_float2(r0.x * sc, r0.y * sc);
            dst[tid + 256] = make_float2(r1.x * sc, r1.y * sc);
        }
    }
}

// K5: irfft along v for 4 rows h0..h0+3 (pocketfft c2r: imag of DC/Nyquist ignored).
__global__ __launch_bounds__(256) void k_row_irfft(const float2* __restrict__ ZT,
                                                   float* __restrict__ out) {
    __shared__ float2 b0[2048], b1[2048], tbl[256];
    int tid = threadIdx.x;
    int no = blockIdx.x / 128;
    int h0 = (blockIdx.x % 128) * 4;
    build_tbl(tbl, tid);
#pragma unroll
    for (int i = 0; i < 5; ++i) {
        int e = tid + 256 * i;
        if (e < 1028) {
            int k = e & 3, vv = e >> 2;
            float2 val = ZT[((size_t)no * 257 + vv) * 512 + h0 + k];
            if (vv == 0 || vv == 256) val.y = 0.0f;
            b0[k * 512 + vv] = val;
        }
    }
    __syncthreads();
#pragma unroll
    for (int i = 0; i < 4; ++i) {
        int e = tid + 256 * i;
        if (e < 1020) {
            int k = e & 3, vv = 257 + (e >> 2);
            float2 s = b0[k * 512 + (512 - vv)];
            b0[k * 512 + vv] = make_float2(s.x, -s.y);
        }
    }
    __syncthreads();
    float2* res = fft512<4>(b0, b1, tbl, tid, true);
    const float sc = 1.0f / 512.0f;
#pragma unroll
    for (int k = 0; k < 4; ++k) {
        float* dst = out + ((size_t)no * 512 + h0 + k) * 512;
        dst[tid]       = res[k * 512 + tid].x * sc;
        dst[tid + 256] = res[k * 512 + tid + 256].x * sc;
    }
}

extern "C" void kernel_launch(void* const* d_in, const int* in_sizes, int n_in,
                              void* d_out, int out_size, void* d_ws, size_t ws_size,
                              hipStream_t stream) {
    const float* x  = (const float*)d_in[0];
    const float* wr = (const float*)d_in[1];
    const float* wi = (const float*)d_in[2];
    const float* br = (const float*)d_in[3];
    const float* bi = (const float*)d_in[4];
    float* out = (float*)d_out;

    const size_t bufElems = (size_t)128 * 257 * 512;  // complex elements
    float2* A = (float2*)d_ws;
    float2* B = A + bufElems;

    k_row_rfft<<<128 * 512, 256, 0, stream>>>(x, A);                 // x -> G (A)
    k_col_fft<<<128 * 65, 256, 0, stream>>>(A, B);                   // G -> XT (B)
    k_conv<<<8 * 257 * 8, 256, 0, stream>>>(B, A, wr, wi, br, bi);   // XT -> YT (A)
    k_col_ifft<<<128 * 65, 256, 0, stream>>>(A, B);                  // YT -> ZT (B)
    k_row_irfft<<<128 * 128, 256, 0, stream>>>(B, out);              // ZT -> out
}

// Round 2
// 721.269 us; speedup vs baseline: 1.2263x; 1.0698x over previous
//
#include <hip/hip_runtime.h>
#include <math.h>

#define PI_F 3.14159265358979323846f

// FFT LDS padding: +1 complex slot every 16 -> breaks radix-4's power-of-2
// write strides (16-way conflicts) down to <=4-way while keeping stride-1
// runs contiguous within 16-blocks.
#define FI(i) ((i) + ((i) >> 4))
#define CSTRIDE 544  // padded per-column stride: 512 + 32

__device__ inline float2 cmulf(float2 a, float2 b) {
    return make_float2(a.x * b.x - a.y * b.y, a.x * b.y + a.y * b.x);
}
__device__ inline float2 cadd(float2 a, float2 b) { return make_float2(a.x + b.x, a.y + b.y); }
__device__ inline float2 csub(float2 a, float2 b) { return make_float2(a.x - b.x, a.y - b.y); }

// Complex MAC: a += w * v
__device__ inline void cmac(float2& a, float2 w, float2 v) {
    a.x = fmaf(w.x, v.x, a.x);
    a.x = fmaf(-w.y, v.y, a.x);
    a.y = fmaf(w.x, v.y, a.y);
    a.y = fmaf(w.y, v.x, a.y);
}

// tbl[k] = exp(-2*pi*i*k/512), k in [0,128) — only w1 twiddles needed;
// w2/w3 are squared/cubed in registers.
__device__ inline void build_tbl128(float2* tbl, int tid) {
    if (tid < 128) {
        float ang = -2.0f * PI_F * (float)tid * (1.0f / 512.0f);
        tbl[tid] = make_float2(cosf(ang), sinf(ang));
    }
}

// 512-point Stockham FFT, radix-4 x4 + radix-2 final (5 stages, 5 barriers),
// over NCOLS interleaved transforms (NCOLS must be even; we use 4).
// Data at a[col*CSTRIDE + FI(i)]; b is ping-pong. 256 threads.
// Verified against direct DFT algebra (OTFFT DIF form):
//   y[4p+0] = (a+c)+(b+d); y[4p+1] = w1*((a-c)-i(b-d));
//   y[4p+2] = w1^2*((a+c)-(b+d)); y[4p+3] = w1^3*((a-c)+i(b-d));  w1=exp(-2pi i p/n)
// inv: conjugate w1 and flip the sign of i(b-d). No 1/N scaling here.
template <int NCOLS>
__device__ inline float2* fft512_r4(float2* a, float2* b, const float2* tbl, int tid, bool inv) {
    const int bf = tid & 127;  // butterfly index within a column
    const int cp = tid >> 7;   // column parity this thread covers
#pragma unroll
    for (int st = 0; st < 4; ++st) {
        const int slog = 2 * st;
        const int s = 1 << slog;
        const int p = bf >> slog;
        const int q = bf & (s - 1);
        float2 w1 = tbl[p << slog];
        if (inv) w1.y = -w1.y;
        const float2 w2 = cmulf(w1, w1);
        const float2 w3 = cmulf(w2, w1);
        const int i0 = bf;                  // q + s*p
        const int ob = q + (p << (slog + 2));  // q + 4*s*p
#pragma unroll
        for (int t = 0; t < NCOLS / 2; ++t) {
            const int cc = cp + 2 * t;
            const float2* ac = a + cc * CSTRIDE;
            float2* bc = b + cc * CSTRIDE;
            float2 A = ac[FI(i0)];
            float2 B = ac[FI(i0 + 128)];
            float2 C = ac[FI(i0 + 256)];
            float2 D = ac[FI(i0 + 384)];
            float2 apc = cadd(A, C), amc = csub(A, C);
            float2 bpd = cadd(B, D), bmd = csub(B, D);
            float2 jb = make_float2(-bmd.y, bmd.x);  // i*(B-D)
            if (inv) { jb.x = -jb.x; jb.y = -jb.y; }
            bc[FI(ob)]           = cadd(apc, bpd);
            bc[FI(ob + s)]       = cmulf(csub(amc, jb), w1);
            bc[FI(ob + 2 * s)]   = cmulf(csub(apc, bpd), w2);
            bc[FI(ob + 3 * s)]   = cmulf(cadd(amc, jb), w3);
        }
        __syncthreads();
        float2* tmp = a; a = b; b = tmp;
    }
    // final radix-2 stage: n=2, s=256, twiddle-free
    {
#pragma unroll
        for (int cc = 0; cc < NCOLS; ++cc) {
            const float2* ac = a + cc * CSTRIDE;
            float2* bc = b + cc * CSTRIDE;
            float2 A = ac[FI(tid)];
            float2 B = ac[FI(tid + 256)];
            bc[FI(tid)]       = cadd(A, B);
            bc[FI(tid + 256)] = csub(A, B);
        }
        __syncthreads();
        float2* tmp = a; a = b; b = tmp;
    }
    return a;
}

// K1: real FFT of rows of x, 4 rows per block.
__global__ __launch_bounds__(256) void k_row_rfft(const float* __restrict__ x,
                                                  float2* __restrict__ G) {
    __shared__ float2 b0[4 * CSTRIDE], b1[4 * CSTRIDE], tbl[128];
    int tid = threadIdx.x;
    int nc = blockIdx.x >> 7;
    int h0 = (blockIdx.x & 127) * 4;
    build_tbl128(tbl, tid);
    const float4* xr = (const float4*)(x + ((size_t)nc * 512 + h0) * 512);
#pragma unroll
    for (int j = 0; j < 2; ++j) {
        int t4 = tid + 256 * j;  // float4 index in [0,512)
        float4 v = xr[t4];
        int e = t4 * 4;          // element index in [0,2048)
        int k = e >> 9, i = e & 511;
        // i % 16 in {0,4,8,12} -> FI contiguous over the 4 elems
        float2* dst = b0 + k * CSTRIDE + FI(i);
        dst[0] = make_float2(v.x, 0.0f);
        dst[1] = make_float2(v.y, 0.0f);
        dst[2] = make_float2(v.z, 0.0f);
        dst[3] = make_float2(v.w, 0.0f);
    }
    __syncthreads();
    float2* res = fft512_r4<4>(b0, b1, tbl, tid, false);
#pragma unroll
    for (int k = 0; k < 4; ++k) {
        float2* g = G + ((size_t)(nc * 512 + h0 + k)) * 257;
        g[tid] = res[k * CSTRIDE + FI(tid)];
        if (tid == 0) g[256] = res[k * CSTRIDE + FI(256)];
    }
}

// K2: FFT along h for 4 adjacent columns v0..v0+3.
__global__ __launch_bounds__(256) void k_col_fft(const float2* __restrict__ G,
                                                 float2* __restrict__ XT) {
    __shared__ float2 b0[4 * CSTRIDE], b1[4 * CSTRIDE], tbl[128];
    int tid = threadIdx.x;
    int nc = blockIdx.x / 65;
    int v0 = (blockIdx.x % 65) * 4;
    build_tbl128(tbl, tid);
#pragma unroll
    for (int i = 0; i < 8; ++i) {
        int e = tid + 256 * i;
        int k = e & 3, h = e >> 2;
        int v = v0 + k;
        float2 val = make_float2(0.0f, 0.0f);
        if (v < 257) val = G[((size_t)nc * 512 + h) * 257 + v];
        b0[k * CSTRIDE + FI(h)] = val;
    }
    __syncthreads();
    float2* res = fft512_r4<4>(b0, b1, tbl, tid, false);
#pragma unroll
    for (int k = 0; k < 4; ++k) {
        int v = v0 + k;
        if (v < 257) {
            float2* dst = XT + ((size_t)nc * 257 + v) * 512;
            dst[tid]       = res[k * CSTRIDE + FI(tid)];
            dst[tid + 256] = res[k * CSTRIDE + FI(tid + 256)];
        }
    }
}

// K3: complex 3x3 conv, 16->16 channels, zero padding, on the half-spectrum.
// o is wave-uniform (wave wv owns o = 4*wv..4*wv+3, looped in registers);
// lane = u within a 64-wide u-tile. Weights via scalar loads; X tile in
// linear LDS read with contiguous lane-indexed ds_read_b64.
__global__ __launch_bounds__(256, 6) void k_conv(const float2* __restrict__ XT,
                                                 float2* __restrict__ YT,
                                                 const float* __restrict__ wr,
                                                 const float* __restrict__ wi,
                                                 const float* __restrict__ br,
                                                 const float* __restrict__ bi) {
    __shared__ float2 Xs[16 * 3 * 66];  // [c][dv][uu], linear, no padding
    int tid = threadIdx.x;
    int bid = blockIdx.x;
    int ut = bid & 7;
    int rest = bid >> 3;
    int v = rest % 257;
    int n = rest / 257;
    int u0 = ut * 64;

    for (int l = tid; l < 3168; l += 256) {
        int c = l / 198;
        int rem = l - c * 198;
        int dv = rem / 66;
        int uu = rem - dv * 66;
        int vg = v - 1 + dv;
        int ug = u0 - 1 + uu;
        float2 val = make_float2(0.0f, 0.0f);
        if (vg >= 0 && vg < 257 && ug >= 0 && ug < 512)
            val = XT[(((size_t)n * 16 + c) * 257 + vg) * 512 + ug];
        Xs[l] = val;
    }
    __syncthreads();

    int lane = tid & 63;
    int wv = __builtin_amdgcn_readfirstlane(tid >> 6);
    int o0 = wv * 4;

    float2 acc[4];
#pragma unroll
    for (int oo = 0; oo < 4; ++oo)
        acc[oo] = make_float2(br[o0 + oo], bi[o0 + oo]);

    for (int c = 0; c < 16; ++c) {
        float2 xv[3][3];
#pragma unroll
        for (int dv = 0; dv < 3; ++dv) {
            const float2* row = &Xs[(c * 3 + dv) * 66];
            xv[dv][0] = row[lane];
            xv[dv][1] = row[lane + 1];
            xv[dv][2] = row[lane + 2];
        }
#pragma unroll
        for (int oo = 0; oo < 4; ++oo) {
            const float* wrp = wr + ((size_t)(c * 16 + o0 + oo)) * 9;
            const float* wip = wi + ((size_t)(c * 16 + o0 + oo)) * 9;
            float wre[9], wim[9];
#pragma unroll
            for (int t = 0; t < 9; ++t) { wre[t] = wrp[t]; wim[t] = wip[t]; }
#pragma unroll
            for (int dv = 0; dv < 3; ++dv) {
                int kw = 2 - dv;
#pragma unroll
                for (int kh = 0; kh < 3; ++kh) {
                    int t = kh * 3 + kw;
                    float2 w = make_float2(wre[t], wim[t]);
                    cmac(acc[oo], w, xv[dv][2 - kh]);
                }
            }
        }
    }

#pragma unroll
    for (int oo = 0; oo < 4; ++oo) {
        YT[(((size_t)n * 16 + o0 + oo) * 257 + v) * 512 + u0 + lane] = acc[oo];
    }
}

// K4: inverse FFT along u (scale 1/512) for 4 columns.
__global__ __launch_bounds__(256) void k_col_ifft(const float2* __restrict__ YT,
                                                  float2* __restrict__ ZT) {
    __shared__ float2 b0[4 * CSTRIDE], b1[4 * CSTRIDE], tbl[128];
    int tid = threadIdx.x;
    int no = blockIdx.x / 65;
    int v0 = (blockIdx.x % 65) * 4;
    build_tbl128(tbl, tid);
#pragma unroll
    for (int k = 0; k < 4; ++k) {
        int v = v0 + k;
        const float2* src = YT + ((size_t)no * 257 + (v < 257 ? v : 256)) * 512;
        b0[k * CSTRIDE + FI(tid)]       = src[tid];
        b0[k * CSTRIDE + FI(tid + 256)] = src[tid + 256];
    }
    __syncthreads();
    float2* res = fft512_r4<4>(b0, b1, tbl, tid, true);
    const float sc = 1.0f / 512.0f;
#pragma unroll
    for (int k = 0; k < 4; ++k) {
        int v = v0 + k;
        if (v < 257) {
            float2* dst = ZT + ((size_t)no * 257 + v) * 512;
            float2 r0 = res[k * CSTRIDE + FI(tid)];
            float2 r1 = res[k * CSTRIDE + FI(tid + 256)];
            dst[tid]       = make_float2(r0.x * sc, r0.y * sc);
            dst[tid + 256] = make_float2(r1.x * sc, r1.y * sc);
        }
    }
}

// K5: irfft along v for 4 rows h0..h0+3 (imag of DC/Nyquist ignored).
__global__ __launch_bounds__(256) void k_row_irfft(const float2* __restrict__ ZT,
                                                   float* __restrict__ out) {
    __shared__ float2 b0[4 * CSTRIDE], b1[4 * CSTRIDE], tbl[128];
    int tid = threadIdx.x;
    int no = blockIdx.x >> 7;
    int h0 = (blockIdx.x & 127) * 4;
    build_tbl128(tbl, tid);
#pragma unroll
    for (int i = 0; i < 5; ++i) {
        int e = tid + 256 * i;
        if (e < 1028) {
            int k = e & 3, vv = e >> 2;
            float2 val = ZT[((size_t)no * 257 + vv) * 512 + h0 + k];
            if (vv == 0 || vv == 256) val.y = 0.0f;
            b0[k * CSTRIDE + FI(vv)] = val;
        }
    }
    __syncthreads();
#pragma unroll
    for (int i = 0; i < 4; ++i) {
        int e = tid + 256 * i;
        if (e < 1020) {
            int k = e & 3, vv = 257 + (e >> 2);
            float2 s = b0[k * CSTRIDE + FI(512 - vv)];
            b0[k * CSTRIDE + FI(vv)] = make_float2(s.x, -s.y);
        }
    }
    __syncthreads();
    float2* res = fft512_r4<4>(b0, b1, tbl, tid, true);
    const float sc = 1.0f / 512.0f;
#pragma unroll
    for (int k = 0; k < 4; ++k) {
        float* dst = out + ((size_t)no * 512 + h0 + k) * 512;
        dst[tid]       = res[k * CSTRIDE + FI(tid)].x * sc;
        dst[tid + 256] = res[k * CSTRIDE + FI(tid + 256)].x * sc;
    }
}

extern "C" void kernel_launch(void* const* d_in, const int* in_sizes, int n_in,
                              void* d_out, int out_size, void* d_ws, size_t ws_size,
                              hipStream_t stream) {
    const float* x  = (const float*)d_in[0];
    const float* wr = (const float*)d_in[1];
    const float* wi = (const float*)d_in[2];
    const float* br = (const float*)d_in[3];
    const float* bi = (const float*)d_in[4];
    float* out = (float*)d_out;

    const size_t bufElems = (size_t)128 * 257 * 512;  // complex elements
    float2* A = (float2*)d_ws;
    float2* B = A + bufElems;

    k_row_rfft<<<128 * 128, 256, 0, stream>>>(x, A);                 // x -> G (A)
    k_col_fft<<<128 * 65, 256, 0, stream>>>(A, B);                   // G -> XT (B)
    k_conv<<<8 * 257 * 8, 256, 0, stream>>>(B, A, wr, wi, br, bi);   // XT -> YT (A)
    k_col_ifft<<<128 * 65, 256, 0, stream>>>(A, B);                  // YT -> ZT (B)
    k_row_irfft<<<128 * 128, 256, 0, stream>>>(B, out);              // ZT -> out
}

// Round 3
// 714.337 us; speedup vs baseline: 1.2382x; 1.0097x over previous
//
#include <hip/hip_runtime.h>
#include <math.h>

#define PI_F 3.14159265358979323846f

// FFT LDS padding: +1 complex slot every 16 -> breaks radix-4's power-of-2
// write strides (16-way conflicts) down to <=4-way while keeping stride-1
// runs contiguous within 16-blocks.
#define FI(i) ((i) + ((i) >> 4))
#define CSTRIDE 544  // padded per-column stride: 512 + 32

__device__ inline float2 cmulf(float2 a, float2 b) {
    return make_float2(a.x * b.x - a.y * b.y, a.x * b.y + a.y * b.x);
}
__device__ inline float2 cadd(float2 a, float2 b) { return make_float2(a.x + b.x, a.y + b.y); }
__device__ inline float2 csub(float2 a, float2 b) { return make_float2(a.x - b.x, a.y - b.y); }

// Bijective chunked XCD remap (grid % 8 == 0): hardware bids with equal
// (bid&7) — i.e. same XCD under round-robin dispatch — get CONSECUTIVE
// logical indices, so line-sharing neighbor blocks hit the same L2.
__device__ inline int xcd_remap(int bid, int q) {
    return (bid & 7) * q + (bid >> 3);
}

// tbl[k] = exp(-2*pi*i*k/512), k in [0,128) — only w1 twiddles needed;
// w2/w3 are squared/cubed in registers.
__device__ inline void build_tbl128(float2* tbl, int tid) {
    if (tid < 128) {
        float ang = -2.0f * PI_F * (float)tid * (1.0f / 512.0f);
        tbl[tid] = make_float2(cosf(ang), sinf(ang));
    }
}

// 512-point Stockham FFT, radix-4 x4 + radix-2 final (5 stages, 5 barriers),
// over NCOLS interleaved transforms (NCOLS must be even; we use 4).
// Data at a[col*CSTRIDE + FI(i)]; b is ping-pong. 256 threads.
//   y[4p+0] = (a+c)+(b+d); y[4p+1] = w1*((a-c)-i(b-d));
//   y[4p+2] = w1^2*((a+c)-(b+d)); y[4p+3] = w1^3*((a-c)+i(b-d));  w1=exp(-2pi i p/n)
// inv: conjugate w1 and flip the sign of i(b-d). No 1/N scaling here.
template <int NCOLS>
__device__ inline float2* fft512_r4(float2* a, float2* b, const float2* tbl, int tid, bool inv) {
    const int bf = tid & 127;  // butterfly index within a column
    const int cp = tid >> 7;   // column parity this thread covers
#pragma unroll
    for (int st = 0; st < 4; ++st) {
        const int slog = 2 * st;
        const int s = 1 << slog;
        const int p = bf >> slog;
        const int q = bf & (s - 1);
        float2 w1 = tbl[p << slog];
        if (inv) w1.y = -w1.y;
        const float2 w2 = cmulf(w1, w1);
        const float2 w3 = cmulf(w2, w1);
        const int i0 = bf;                     // q + s*p
        const int ob = q + (p << (slog + 2));  // q + 4*s*p
#pragma unroll
        for (int t = 0; t < NCOLS / 2; ++t) {
            const int cc = cp + 2 * t;
            const float2* ac = a + cc * CSTRIDE;
            float2* bc = b + cc * CSTRIDE;
            float2 A = ac[FI(i0)];
            float2 B = ac[FI(i0 + 128)];
            float2 C = ac[FI(i0 + 256)];
            float2 D = ac[FI(i0 + 384)];
            float2 apc = cadd(A, C), amc = csub(A, C);
            float2 bpd = cadd(B, D), bmd = csub(B, D);
            float2 jb = make_float2(-bmd.y, bmd.x);  // i*(B-D)
            if (inv) { jb.x = -jb.x; jb.y = -jb.y; }
            bc[FI(ob)]           = cadd(apc, bpd);
            bc[FI(ob + s)]       = cmulf(csub(amc, jb), w1);
            bc[FI(ob + 2 * s)]   = cmulf(csub(apc, bpd), w2);
            bc[FI(ob + 3 * s)]   = cmulf(cadd(amc, jb), w3);
        }
        __syncthreads();
        float2* tmp = a; a = b; b = tmp;
    }
    // final radix-2 stage: n=2, s=256, twiddle-free
    {
#pragma unroll
        for (int cc = 0; cc < NCOLS; ++cc) {
            const float2* ac = a + cc * CSTRIDE;
            float2* bc = b + cc * CSTRIDE;
            float2 A = ac[FI(tid)];
            float2 B = ac[FI(tid + 256)];
            bc[FI(tid)]       = cadd(A, B);
            bc[FI(tid + 256)] = csub(A, B);
        }
        __syncthreads();
        float2* tmp = a; a = b; b = tmp;
    }
    return a;
}

// K1: real FFT of rows of x, 4 rows per block. Block 0 additionally
// precomputes wsum = wr + wi into d_out's head (k_conv reads it before K5
// overwrites d_out; stream order makes this safe).
__global__ __launch_bounds__(256) void k_row_rfft(const float* __restrict__ x,
                                                  float2* __restrict__ G,
                                                  const float* __restrict__ wr,
                                                  const float* __restrict__ wi,
                                                  float* __restrict__ wsum) {
    __shared__ float2 b0[4 * CSTRIDE], b1[4 * CSTRIDE], tbl[128];
    int tid = threadIdx.x;
    int nc = blockIdx.x >> 7;
    int h0 = (blockIdx.x & 127) * 4;
    if (blockIdx.x == 0) {
        for (int l = tid; l < 2304; l += 256) wsum[l] = wr[l] + wi[l];
    }
    build_tbl128(tbl, tid);
    const float4* xr = (const float4*)(x + ((size_t)nc * 512 + h0) * 512);
#pragma unroll
    for (int j = 0; j < 2; ++j) {
        int t4 = tid + 256 * j;  // float4 index in [0,512)
        float4 v = xr[t4];
        int e = t4 * 4;          // element index in [0,2048)
        int k = e >> 9, i = e & 511;
        float2* dst = b0 + k * CSTRIDE + FI(i);
        dst[0] = make_float2(v.x, 0.0f);
        dst[1] = make_float2(v.y, 0.0f);
        dst[2] = make_float2(v.z, 0.0f);
        dst[3] = make_float2(v.w, 0.0f);
    }
    __syncthreads();
    float2* res = fft512_r4<4>(b0, b1, tbl, tid, false);
#pragma unroll
    for (int k = 0; k < 4; ++k) {
        float2* g = G + ((size_t)(nc * 512 + h0 + k)) * 257;
        g[tid] = res[k * CSTRIDE + FI(tid)];
        if (tid == 0) g[256] = res[k * CSTRIDE + FI(256)];
    }
}

// K2: FFT along h for 4 adjacent columns v0..v0+3. XCD-chunk swizzled so
// v-group neighbors (which share 128-B lines of G) run on the same XCD.
__global__ __launch_bounds__(256) void k_col_fft(const float2* __restrict__ G,
                                                 float2* __restrict__ XT) {
    __shared__ float2 b0[4 * CSTRIDE], b1[4 * CSTRIDE], tbl[128];
    int tid = threadIdx.x;
    int l = xcd_remap(blockIdx.x, 1040);  // grid = 8320
    int nc = l / 65;
    int v0 = (l % 65) * 4;
    build_tbl128(tbl, tid);
#pragma unroll
    for (int i = 0; i < 8; ++i) {
        int e = tid + 256 * i;
        int k = e & 3, h = e >> 2;
        int v = v0 + k;
        float2 val = make_float2(0.0f, 0.0f);
        if (v < 257) val = G[((size_t)nc * 512 + h) * 257 + v];
        b0[k * CSTRIDE + FI(h)] = val;
    }
    __syncthreads();
    float2* res = fft512_r4<4>(b0, b1, tbl, tid, false);
#pragma unroll
    for (int k = 0; k < 4; ++k) {
        int v = v0 + k;
        if (v < 257) {
            float2* dst = XT + ((size_t)nc * 257 + v) * 512;
            dst[tid]       = res[k * CSTRIDE + FI(tid)];
            dst[tid + 256] = res[k * CSTRIDE + FI(tid + 256)];
        }
    }
}

// K3: complex 3x3 conv, 16->16 channels, zero padding, on the half-spectrum.
// o is wave-uniform (wave wv owns o = 4*wv..4*wv+3); lane = u. Weights via
// scalar loads. Gauss 3-mult complex MAC: P=sum wr*xr, Q=sum wi*xi,
// R=sum (wr+wi)*(xr+xi); re=P-Q, im=R-P-Q. (wr+wi) comes precomputed (wsm)
// so no VALU is spent on it; sx=xr+xi is shared across 4 o and 3 kh taps.
__global__ __launch_bounds__(256, 6) void k_conv(const float2* __restrict__ XT,
                                                 float2* __restrict__ YT,
                                                 const float* __restrict__ wr,
                                                 const float* __restrict__ wi,
                                                 const float* __restrict__ wsm,
                                                 const float* __restrict__ br,
                                                 const float* __restrict__ bi) {
    __shared__ float2 Xs[16 * 3 * 66];  // [c][dv][uu], linear, no padding
    int tid = threadIdx.x;
    int bid = blockIdx.x;
    int ut = bid & 7;
    int rest = bid >> 3;
    int v = rest % 257;
    int n = rest / 257;
    int u0 = ut * 64;

    for (int l = tid; l < 3168; l += 256) {
        int c = l / 198;
        int rem = l - c * 198;
        int dv = rem / 66;
        int uu = rem - dv * 66;
        int vg = v - 1 + dv;
        int ug = u0 - 1 + uu;
        float2 val = make_float2(0.0f, 0.0f);
        if (vg >= 0 && vg < 257 && ug >= 0 && ug < 512)
            val = XT[(((size_t)n * 16 + c) * 257 + vg) * 512 + ug];
        Xs[l] = val;
    }
    __syncthreads();

    int lane = tid & 63;
    int wv = __builtin_amdgcn_readfirstlane(tid >> 6);
    int o0 = wv * 4;

    float accP[4] = {0.f, 0.f, 0.f, 0.f};
    float accQ[4] = {0.f, 0.f, 0.f, 0.f};
    float accR[4] = {0.f, 0.f, 0.f, 0.f};

    for (int c = 0; c < 16; ++c) {
        float2 xv[3][3];
        float sx[3][3];
#pragma unroll
        for (int dv = 0; dv < 3; ++dv) {
            const float2* row = &Xs[(c * 3 + dv) * 66];
            xv[dv][0] = row[lane];
            xv[dv][1] = row[lane + 1];
            xv[dv][2] = row[lane + 2];
            sx[dv][0] = xv[dv][0].x + xv[dv][0].y;
            sx[dv][1] = xv[dv][1].x + xv[dv][1].y;
            sx[dv][2] = xv[dv][2].x + xv[dv][2].y;
        }
#pragma unroll
        for (int oo = 0; oo < 4; ++oo) {
            const float* wrp = wr  + ((size_t)(c * 16 + o0 + oo)) * 9;
            const float* wip = wi  + ((size_t)(c * 16 + o0 + oo)) * 9;
            const float* wsp = wsm + ((size_t)(c * 16 + o0 + oo)) * 9;
            float wre[9], wim[9], wsu[9];
#pragma unroll
            for (int t = 0; t < 9; ++t) {
                wre[t] = wrp[t]; wim[t] = wip[t]; wsu[t] = wsp[t];
            }
#pragma unroll
            for (int dv = 0; dv < 3; ++dv) {
                int kw = 2 - dv;
#pragma unroll
                for (int kh = 0; kh < 3; ++kh) {
                    int t = kh * 3 + kw;
                    int xj = 2 - kh;
                    accP[oo] = fmaf(wre[t], xv[dv][xj].x, accP[oo]);
                    accQ[oo] = fmaf(wim[t], xv[dv][xj].y, accQ[oo]);
                    accR[oo] = fmaf(wsu[t], sx[dv][xj],  accR[oo]);
                }
            }
        }
    }

#pragma unroll
    for (int oo = 0; oo < 4; ++oo) {
        float re = accP[oo] - accQ[oo] + br[o0 + oo];
        float im = accR[oo] - accP[oo] - accQ[oo] + bi[o0 + oo];
        YT[(((size_t)n * 16 + o0 + oo) * 257 + v) * 512 + u0 + lane] =
            make_float2(re, im);
    }
}

// K4: inverse FFT along u (scale 1/512) for 4 columns.
__global__ __launch_bounds__(256) void k_col_ifft(const float2* __restrict__ YT,
                                                  float2* __restrict__ ZT) {
    __shared__ float2 b0[4 * CSTRIDE], b1[4 * CSTRIDE], tbl[128];
    int tid = threadIdx.x;
    int no = blockIdx.x / 65;
    int v0 = (blockIdx.x % 65) * 4;
    build_tbl128(tbl, tid);
#pragma unroll
    for (int k = 0; k < 4; ++k) {
        int v = v0 + k;
        const float2* src = YT + ((size_t)no * 257 + (v < 257 ? v : 256)) * 512;
        b0[k * CSTRIDE + FI(tid)]       = src[tid];
        b0[k * CSTRIDE + FI(tid + 256)] = src[tid + 256];
    }
    __syncthreads();
    float2* res = fft512_r4<4>(b0, b1, tbl, tid, true);
    const float sc = 1.0f / 512.0f;
#pragma unroll
    for (int k = 0; k < 4; ++k) {
        int v = v0 + k;
        if (v < 257) {
            float2* dst = ZT + ((size_t)no * 257 + v) * 512;
            float2 r0 = res[k * CSTRIDE + FI(tid)];
            float2 r1 = res[k * CSTRIDE + FI(tid + 256)];
            dst[tid]       = make_float2(r0.x * sc, r0.y * sc);
            dst[tid + 256] = make_float2(r1.x * sc, r1.y * sc);
        }
    }
}

// K5: irfft along v for 4 rows h0..h0+3 (imag of DC/Nyquist ignored).
// XCD-chunk swizzled so h-group neighbors (sharing ZT lines) co-locate.
__global__ __launch_bounds__(256) void k_row_irfft(const float2* __restrict__ ZT,
                                                   float* __restrict__ out) {
    __shared__ float2 b0[4 * CSTRIDE], b1[4 * CSTRIDE], tbl[128];
    int tid = threadIdx.x;
    int l = xcd_remap(blockIdx.x, 2048);  // grid = 16384
    int no = l >> 7;
    int h0 = (l & 127) * 4;
    build_tbl128(tbl, tid);
#pragma unroll
    for (int i = 0; i < 5; ++i) {
        int e = tid + 256 * i;
        if (e < 1028) {
            int k = e & 3, vv = e >> 2;
            float2 val = ZT[((size_t)no * 257 + vv) * 512 + h0 + k];
            if (vv == 0 || vv == 256) val.y = 0.0f;
            b0[k * CSTRIDE + FI(vv)] = val;
        }
    }
    __syncthreads();
#pragma unroll
    for (int i = 0; i < 4; ++i) {
        int e = tid + 256 * i;
        if (e < 1020) {
            int k = e & 3, vv = 257 + (e >> 2);
            float2 s = b0[k * CSTRIDE + FI(512 - vv)];
            b0[k * CSTRIDE + FI(vv)] = make_float2(s.x, -s.y);
        }
    }
    __syncthreads();
    float2* res = fft512_r4<4>(b0, b1, tbl, tid, true);
    const float sc = 1.0f / 512.0f;
#pragma unroll
    for (int k = 0; k < 4; ++k) {
        float* dst = out + ((size_t)no * 512 + h0 + k) * 512;
        dst[tid]       = res[k * CSTRIDE + FI(tid)].x * sc;
        dst[tid + 256] = res[k * CSTRIDE + FI(tid + 256)].x * sc;
    }
}

extern "C" void kernel_launch(void* const* d_in, const int* in_sizes, int n_in,
                              void* d_out, int out_size, void* d_ws, size_t ws_size,
                              hipStream_t stream) {
    const float* x  = (const float*)d_in[0];
    const float* wr = (const float*)d_in[1];
    const float* wi = (const float*)d_in[2];
    const float* br = (const float*)d_in[3];
    const float* bi = (const float*)d_in[4];
    float* out = (float*)d_out;

    const size_t bufElems = (size_t)128 * 257 * 512;  // complex elements
    float2* A = (float2*)d_ws;
    float2* B = A + bufElems;
    // wsum (wr+wi, 2304 floats) is stashed at the head of d_out: written by
    // K1, read by k_conv, then fully overwritten by K5. Stream-ordered safe.
    float* wsum = out;

    k_row_rfft<<<128 * 128, 256, 0, stream>>>(x, A, wr, wi, wsum);       // x -> G (A)
    k_col_fft<<<128 * 65, 256, 0, stream>>>(A, B);                       // G -> XT (B)
    k_conv<<<8 * 257 * 8, 256, 0, stream>>>(B, A, wr, wi, wsum, br, bi); // XT -> YT (A)
    k_col_ifft<<<128 * 65, 256, 0, stream>>>(A, B);                      // YT -> ZT (B)
    k_row_irfft<<<128 * 128, 256, 0, stream>>>(B, out);                  // ZT -> out
}